// Round 15
// baseline (139.729 us; speedup 1.0000x reference)
//
#include <hip/hip_runtime.h>

typedef float  v4f    __attribute__((ext_vector_type(4)));
typedef float  f32x4  __attribute__((ext_vector_type(4)));
typedef short  bf16x8 __attribute__((ext_vector_type(8)));
typedef short  bf16x4 __attribute__((ext_vector_type(4)));

namespace {
constexpr int XBSTR = 264;   // xbf row stride (shorts)
constexpr int XDT   = 24;    // xdT row stride (shorts); 48 B, b128-aligned
constexpr int MWC   = 129;   // mw row stride (f32)
constexpr int ATS   = 260;   // att row stride (shorts); 8B-aligned rows for b64 reads
constexpr int MSTR  = 72;    // mbf/abf row stride (shorts)
constexpr int FRAG_SLOTS = 5120;

__device__ __forceinline__ float fsilu(float v){ return v/(1.f+__expf(-v)); }
__device__ __forceinline__ float fsigm(float v){ return 1.f/(1.f+__expf(-v)); }

// fp32 pair -> packed bf16x2 via the HW instruction (1 VALU op / 2 elems)
__device__ __forceinline__ unsigned f2bf2(float a, float b){
  unsigned r;
  asm("v_cvt_pk_bf16_f32 %0, %1, %2" : "=v"(r) : "v"(a), "v"(b));
  return r;
}
__device__ __forceinline__ short f2bf(float f){   // scalar: RNE, matches cvt_pk
  unsigned u = __builtin_bit_cast(unsigned, f);
  return (short)((u + 0x7FFFu + ((u>>16)&1u)) >> 16);
}
__device__ __forceinline__ float bf2f(short s){
  unsigned u = ((unsigned)(unsigned short)s) << 16;
  return __builtin_bit_cast(float, u);
}

// ---- B-fragment getters: frag table in ws (fast) or on-the-fly (fallback) ----
template<bool USE_WS>
__device__ __forceinline__ bf16x8 get_bd(const bf16x8* wsf, const float* Wd,
                                         int nt, int ks, int l){
  if constexpr (USE_WS) return wsf[(nt*8 + ks)*64 + l];
  bf16x8 f;
  #pragma unroll
  for (int j = 0; j < 8; ++j) f[j] = f2bf(Wd[(ks*32 + (l>>4)*8 + j)*64 + nt*16 + (l&15)]);
  return f;
}
template<bool USE_WS>
__device__ __forceinline__ bf16x8 get_bc(const bf16x8* wsf, const float* Wc,
                                         int nt, int ks, int l){
  if constexpr (USE_WS) return wsf[2048 + (nt*2 + ks)*64 + l];
  const int col = nt*16 + (l&15), cw = col>>6, co = col&63;
  bf16x8 f;
  #pragma unroll
  for (int j = 0; j < 8; ++j) f[j] = f2bf(Wc[co*128 + cw*64 + ks*32 + (l>>4)*8 + j]);
  return f;
}
template<bool USE_WS>
__device__ __forceinline__ bf16x8 get_ba(const bf16x8* wsf, const float* Wa,
                                         int nt, int ks, int l){
  if constexpr (USE_WS) return wsf[3072 + (nt*2 + ks)*64 + l];
  const int col = nt*16 + (l&15);
  bf16x8 f;
  #pragma unroll
  for (int j = 0; j < 8; ++j) f[j] = f2bf(Wa[(ks*32 + (l>>4)*8 + j)*256 + col]);
  return f;
}
}

// ---- pre-kernel: pack Wd/Wc/Wa into bf16 MFMA B-fragment tables in ws ----
__global__ __launch_bounds__(256)
void pack_frags(const float* __restrict__ Wd, const float* __restrict__ Wc,
                const float* __restrict__ Wa, bf16x8* __restrict__ wsf)
{
  const int e  = blockIdx.x*256 + threadIdx.x;      // 0..5119
  const int l  = e & 63;
  const int fi = e >> 6;                            // 0..79
  bf16x8 f;
  if (fi < 32) {                                    // Bd: nt(4) x ks(8)
    const int nt = fi >> 3, ks = fi & 7;
    #pragma unroll
    for (int j = 0; j < 8; ++j) f[j] = f2bf(Wd[(ks*32 + (l>>4)*8 + j)*64 + nt*16 + (l&15)]);
  } else if (fi < 48) {                             // Bc: nt(8) x ks(2)
    const int idx = fi - 32, nt = idx >> 1, ks = idx & 1;
    const int col = nt*16 + (l&15), cw = col>>6, co = col&63;
    #pragma unroll
    for (int j = 0; j < 8; ++j) f[j] = f2bf(Wc[co*128 + cw*64 + ks*32 + (l>>4)*8 + j]);
  } else {                                          // Ba: nt(16) x ks(2)
    const int idx = fi - 48, nt = idx >> 1, ks = idx & 1;
    const int col = nt*16 + (l&15);
    #pragma unroll
    for (int j = 0; j < 8; ++j) f[j] = f2bf(Wa[(ks*32 + (l>>4)*8 + j)*256 + col]);
  }
  wsf[e] = f;
}

template<bool USE_WS>
__global__ __launch_bounds__(256, 7)
void fused_gnn_v13(const float* __restrict__ x,
                   const float* __restrict__ Wd, const float* __restrict__ bd,
                   const float* __restrict__ bn1s, const float* __restrict__ bn1b,
                   const float* __restrict__ bn1m, const float* __restrict__ bn1v,
                   const float* __restrict__ Wc,
                   const float* __restrict__ bn2s, const float* __restrict__ bn2b,
                   const float* __restrict__ bn2m, const float* __restrict__ bn2v,
                   const float* __restrict__ Wa, const float* __restrict__ ba,
                   const bf16x8* __restrict__ wsf,
                   float* __restrict__ out)
{
  // ~19.8 KB static LDS (8 blocks/CU by LDS)
  __shared__ short xbf[18*XBSTR];                   // 9504 B; row 17 = tail-clamp garbage target
  __shared__ __align__(16) char uni_raw[3072];      // union: xdT bf16[64][24] | att bf16[5][260]
  __shared__ float mw[5*MWC];                       // 2580 B
  __shared__ short mbf[16*MSTR];                    // 2304 B (rows 5-15 garbage)
  __shared__ short abf[16*MSTR];                    // 2304 B

  short* xdT = (short*)uni_raw;
  short* att = (short*)uni_raw;

  const int tid  = threadIdx.x;
  const int l    = tid & 63;
  const int wv   = tid >> 6;            // wave 0..3
  const int arow = l & 15;
  const int ak8  = (l >> 4) * 8;
  const int b0   = blockIdx.x * 2;      // TWO sequential batches per block
  const int colA = wv*16 + arow;
  const int c4   = l*4;
  const int r0   = tid >> 6;

  // ---- per-lane BN affines in registers (b_down folded into bn1 bias) ----
  const float a1r = bn1s[colA] * rsqrtf(bn1v[colA] + 1e-5f);
  const float b1r = (bd[colA] - bn1m[colA])*a1r + bn1b[colA];
  const float a2r = bn2s[l] * rsqrtf(bn2v[l] + 1e-5f);
  const float b2r = bn2b[l] - bn2m[l]*a2r;

  auto store4 = [&](v4f v, int r){
    uint2 u; u.x = f2bf2(v.x, v.y); u.y = f2bf2(v.z, v.w);
    *(uint2*)&xbf[r*XBSTR + c4] = u;
  };

  // ---- load batch 0 x into regs; stage to LDS; then ISSUE batch 1 loads ----
  v4f xr[2][5];                                     // [it][slot]; compile-time indexed after unroll
  {
    const v4f* x4 = (const v4f*)(x + (size_t)b0 * 4352);
    #pragma unroll
    for (int i = 0; i < 4; ++i) xr[0][i] = x4[i*256 + tid];
    if (tid < 64) xr[0][4] = x4[1024 + tid];
    store4(xr[0][0], r0);      store4(xr[0][1], r0 + 4);
    store4(xr[0][2], r0 + 8);  store4(xr[0][3], r0 + 12);
    if (tid < 64) store4(xr[0][4], 16);
    // prefetch batch 1 (in flight across phases A..E of batch 0)
    const v4f* y4 = x4 + 1088;
    #pragma unroll
    for (int i = 0; i < 4; ++i) xr[1][i] = y4[i*256 + tid];
    if (tid < 64) xr[1][4] = y4[1024 + tid];
  }
  __syncthreads();                                   // bar1: stage -> A (batch 0)

  #pragma unroll
  for (int it = 0; it < 2; ++it) {
    const int b = b0 + it;

    // ---- Phase A (MFMA): xd = silu(bn1(x @ Wd)), M=17, N=64, K=256; -> xdT ----
    {
      f32x4 acc0 = {0.f,0.f,0.f,0.f};
      f32x4 acc1 = {0.f,0.f,0.f,0.f};
      const int rowT = (arow == 0) ? 16 : 17;
      #pragma unroll
      for (int h = 0; h < 2; ++h) {
        bf16x8 Bd[4];
        #pragma unroll
        for (int k4 = 0; k4 < 4; ++k4) Bd[k4] = get_bd<USE_WS>(wsf, Wd, wv, h*4 + k4, l);
        #pragma unroll
        for (int k4 = 0; k4 < 4; ++k4) {
          const int ks = h*4 + k4;
          bf16x8 a0 = *(const bf16x8*)&xbf[arow*XBSTR + ks*32 + ak8];
          acc0 = __builtin_amdgcn_mfma_f32_16x16x32_bf16(a0, Bd[k4], acc0, 0, 0, 0);
          bf16x8 a1 = *(const bf16x8*)&xbf[rowT*XBSTR + ks*32 + ak8];
          acc1 = __builtin_amdgcn_mfma_f32_16x16x32_bf16(a1, Bd[k4], acc1, 0, 0, 0);
        }
      }
      const float s0 = fsilu(acc0[0]*a1r + b1r);
      const float s1 = fsilu(acc0[1]*a1r + b1r);
      const float s2 = fsilu(acc0[2]*a1r + b1r);
      const float s3 = fsilu(acc0[3]*a1r + b1r);
      uint2 u; u.x = f2bf2(s0, s1); u.y = f2bf2(s2, s3);
      *(uint2*)&xdT[colA*XDT + (l>>4)*4] = u;
      if ((l >> 4) == 0)
        xdT[colA*XDT + 16] = f2bf(fsilu(acc1[0]*a1r + b1r));
    }
    __syncthreads();                                 // bar2: A -> B1 (xbf also dead now)

    // ---- batch-1 staging: xbf is free after bar2 of iteration 0 ----
    if (it == 0) {
      store4(xr[1][0], r0);      store4(xr[1][1], r0 + 4);
      store4(xr[1][2], r0 + 8);  store4(xr[1][3], r0 + 12);
      if (tid < 64) store4(xr[1][4], 16);
    }

    // ---- prefetch B2 weight frags ----
    bf16x8 BcT[2][2];
    #pragma unroll
    for (int t = 0; t < 2; ++t)
      #pragma unroll
      for (int ks = 0; ks < 2; ++ks)
        BcT[t][ks] = get_bc<USE_WS>(wsf, Wc, wv*2 + t, ks, l);

    // ---- Phase B1 (split): wave wv computes group g=wv; wave 0 also g=4 ----
    {
      const int i = l;
      #define XDV(r) bf2f(xdT[i*XDT + (r)])
      if (wv == 0) {
        mbf[0*MSTR + i] = f2bf((XDV(0)+XDV(1)+XDV(2)+XDV(3)+XDV(4))*0.2f);
        mbf[4*MSTR + i] = f2bf((XDV(12)+XDV(14)+XDV(16))*(1.f/3.f));
      } else if (wv == 1) {
        mbf[1*MSTR + i] = f2bf((XDV(5)+XDV(7)+XDV(9))*(1.f/3.f));
      } else if (wv == 2) {
        mbf[2*MSTR + i] = f2bf((XDV(6)+XDV(8)+XDV(10))*(1.f/3.f));
      } else {
        mbf[3*MSTR + i] = f2bf((XDV(11)+XDV(13)+XDV(15))*(1.f/3.f));
      }
      #undef XDV
    }
    __syncthreads();                                 // bar3: B1 -> B2 (mbf cross-wave)

    // ---- Phase B2 (MFMA): mw = means @ [Wc1|Wc2], M=5, N=128, wave owns 2 n-tiles ----
    {
      bf16x8 am[2];
      #pragma unroll
      for (int ks = 0; ks < 2; ++ks)
        am[ks] = *(const bf16x8*)&mbf[arow*MSTR + ks*32 + ak8];
      #pragma unroll
      for (int t = 0; t < 2; ++t) {
        const int nt = wv*2 + t;
        f32x4 acc = {0.f,0.f,0.f,0.f};
        #pragma unroll
        for (int ks = 0; ks < 2; ++ks)
          acc = __builtin_amdgcn_mfma_f32_16x16x32_bf16(am[ks], BcT[t][ks], acc, 0, 0, 0);
        if ((l >> 4) == 0) {
          #pragma unroll
          for (int j = 0; j < 4; ++j) mw[j*MWC + nt*16 + arow] = acc[j];
        } else if ((l >> 4) == 1) {
          mw[4*MWC + nt*16 + arow] = acc[0];
        }
      }
    }
    __syncthreads();                                 // bar4: B2 -> B3 (mw cross-wave)

    // ---- prefetch phase-E weight frags ----
    bf16x8 BaT[4][2];
    #pragma unroll
    for (int t = 0; t < 4; ++t)
      #pragma unroll
      for (int ks = 0; ks < 2; ++ks)
        BaT[t][ks] = get_ba<USE_WS>(wsf, Wa, wv*4 + t, ks, l);

    // ---- Phase B3 (split): wave wv computes g=wv; wave 0 also g=4 ----
    {
      const int o = l;
      float m2c[5];
      #pragma unroll
      for (int cc = 0; cc < 5; ++cc) m2c[cc] = mw[cc*MWC + 64 + o];
      auto doG = [&](int g){
        const float bse = mw[g*MWC + o] - m2c[g];
        float s = 0.f;
        #pragma unroll
        for (int cc = 0; cc < 5; ++cc) {
          if (cc != g) s += fsilu((bse + m2c[cc])*a2r + b2r);
        }
        abf[g*MSTR + o] = f2bf(s);
      };
      if (wv == 0) { doG(0); doG(4); }
      else if (wv == 1) doG(1);
      else if (wv == 2) doG(2);
      else doG(3);
    }
    __syncthreads();                                 // bar5: B3 -> E (abf cross-wave)

    // ---- Phase E (MFMA): att = sigmoid(agg @ Wa + ba); sigmoid only where g<5 ----
    {
      bf16x8 ae[2];
      #pragma unroll
      for (int ks = 0; ks < 2; ++ks)
        ae[ks] = *(const bf16x8*)&abf[arow*MSTR + ks*32 + ak8];
      #pragma unroll
      for (int t = 0; t < 4; ++t) {
        const int nt = wv*4 + t;
        const int colE = nt*16 + arow;
        f32x4 acc = {0.f,0.f,0.f,0.f};
        #pragma unroll
        for (int ks = 0; ks < 2; ++ks)
          acc = __builtin_amdgcn_mfma_f32_16x16x32_bf16(ae[ks], BaT[t][ks], acc, 0, 0, 0);
        const float bav = ba[colE];
        const int q4 = l >> 4;
        if (q4 == 0) {
          #pragma unroll
          for (int j = 0; j < 4; ++j)
            att[j*ATS + colE] = f2bf(fsigm(acc[j] + bav));
        } else if (q4 == 1) {
          att[4*ATS + colE] = f2bf(fsigm(acc[0] + bav));
        }
      }
    }
    __syncthreads();                                 // bar6: E -> F (att cross-wave)

    // ---- Phase F: out from f32 regs * att, dwordx4 stores ----
    {
      float* og = out + (size_t)b*4352;
      constexpr int GOF[17] = {0,0,0,0,0,1,2,1,2,1,2,3,4,3,4,3,4};
      auto emit = [&](v4f xv, int k){
        const bf16x4 a4 = *(const bf16x4*)&att[GOF[k]*ATS + c4];
        v4f o;
        o.x = xv.x * bf2f(a4[0]);
        o.y = xv.y * bf2f(a4[1]);
        o.z = xv.z * bf2f(a4[2]);
        o.w = xv.w * bf2f(a4[3]);
        *(v4f*)&og[k*256 + c4] = o;
      };
      emit(xr[it][0], r0);      emit(xr[it][1], r0 + 4);
      emit(xr[it][2], r0 + 8);  emit(xr[it][3], r0 + 12);
      if (tid < 64) emit(xr[it][4], 16);
    }
    if (it == 0) __syncthreads();                    // bar7: att reads -> next iter's xdT writes
  }
}

extern "C" void kernel_launch(void* const* d_in, const int* in_sizes, int n_in,
                              void* d_out, int out_size, void* d_ws, size_t ws_size,
                              hipStream_t stream) {
    (void)n_in; (void)out_size;
    const float* x   = (const float*)d_in[0];
    const float* Wd  = (const float*)d_in[1];
    const float* bd  = (const float*)d_in[2];
    const float* s1  = (const float*)d_in[3];
    const float* b1  = (const float*)d_in[4];
    const float* m1  = (const float*)d_in[5];
    const float* v1  = (const float*)d_in[6];
    const float* Wc  = (const float*)d_in[7];
    const float* s2  = (const float*)d_in[8];
    const float* b2  = (const float*)d_in[9];
    const float* m2  = (const float*)d_in[10];
    const float* v2  = (const float*)d_in[11];
    const float* Wa  = (const float*)d_in[12];
    const float* ba  = (const float*)d_in[13];

    const int Btot = in_sizes[0] / (17 * 256);   // 4096
    const int GRID = Btot / 2;                   // 2048 blocks, 2 batches each
    bf16x8* wsf = (bf16x8*)d_ws;

    if (ws_size >= (size_t)FRAG_SLOTS * 16) {
        pack_frags<<<FRAG_SLOTS/256, 256, 0, stream>>>(Wd, Wc, Wa, wsf);
        fused_gnn_v13<true><<<GRID, 256, 0, stream>>>(
            x, Wd, bd, s1, b1, m1, v1, Wc, s2, b2, m2, v2, Wa, ba,
            wsf, (float*)d_out);
    } else {
        fused_gnn_v13<false><<<GRID, 256, 0, stream>>>(
            x, Wd, bd, s1, b1, m1, v1, Wc, s2, b2, m2, v2, Wa, ba,
            wsf, (float*)d_out);
    }
}

// Round 16
// 87.560 us; speedup vs baseline: 1.5958x; 1.5958x over previous
//
#include <hip/hip_runtime.h>

typedef float  v4f    __attribute__((ext_vector_type(4)));
typedef float  f32x4  __attribute__((ext_vector_type(4)));
typedef short  bf16x8 __attribute__((ext_vector_type(8)));
typedef short  bf16x4 __attribute__((ext_vector_type(4)));

namespace {
constexpr int XBSTR = 264;   // xbf row stride (shorts)
constexpr int XDT   = 24;    // xdT row stride (shorts); 48 B, b128-aligned
constexpr int MWC   = 129;   // mw row stride (f32)
constexpr int ATS   = 260;   // att row stride (shorts); 8B-aligned rows
constexpr int MSTR  = 72;    // mbf/abf row stride (shorts)
constexpr int FRAG_SLOTS = 5120;

__device__ __forceinline__ float fsilu(float v){ return v/(1.f+__expf(-v)); }
__device__ __forceinline__ float fsigm(float v){ return 1.f/(1.f+__expf(-v)); }

__device__ __forceinline__ unsigned f2bf2(float a, float b){
  unsigned r;
  asm("v_cvt_pk_bf16_f32 %0, %1, %2" : "=v"(r) : "v"(a), "v"(b));
  return r;
}
__device__ __forceinline__ short f2bf(float f){   // scalar RNE, matches cvt_pk
  unsigned u = __builtin_bit_cast(unsigned, f);
  return (short)((u + 0x7FFFu + ((u>>16)&1u)) >> 16);
}
__device__ __forceinline__ float bf2f(short s){
  unsigned u = ((unsigned)(unsigned short)s) << 16;
  return __builtin_bit_cast(float, u);
}

template<bool USE_WS>
__device__ __forceinline__ bf16x8 get_bd(const bf16x8* wsf, const float* Wd,
                                         int nt, int ks, int l){
  if constexpr (USE_WS) return wsf[(nt*8 + ks)*64 + l];
  bf16x8 f;
  #pragma unroll
  for (int j = 0; j < 8; ++j) f[j] = f2bf(Wd[(ks*32 + (l>>4)*8 + j)*64 + nt*16 + (l&15)]);
  return f;
}
template<bool USE_WS>
__device__ __forceinline__ bf16x8 get_bc(const bf16x8* wsf, const float* Wc,
                                         int nt, int ks, int l){
  if constexpr (USE_WS) return wsf[2048 + (nt*2 + ks)*64 + l];
  const int col = nt*16 + (l&15), cw = col>>6, co = col&63;
  bf16x8 f;
  #pragma unroll
  for (int j = 0; j < 8; ++j) f[j] = f2bf(Wc[co*128 + cw*64 + ks*32 + (l>>4)*8 + j]);
  return f;
}
template<bool USE_WS>
__device__ __forceinline__ bf16x8 get_ba(const bf16x8* wsf, const float* Wa,
                                         int nt, int ks, int l){
  if constexpr (USE_WS) return wsf[3072 + (nt*2 + ks)*64 + l];
  const int col = nt*16 + (l&15);
  bf16x8 f;
  #pragma unroll
  for (int j = 0; j < 8; ++j) f[j] = f2bf(Wa[(ks*32 + (l>>4)*8 + j)*256 + col]);
  return f;
}
}

__global__ __launch_bounds__(256)
void pack_frags(const float* __restrict__ Wd, const float* __restrict__ Wc,
                const float* __restrict__ Wa, bf16x8* __restrict__ wsf)
{
  const int e  = blockIdx.x*256 + threadIdx.x;      // 0..5119
  const int l  = e & 63;
  const int fi = e >> 6;                            // 0..79
  bf16x8 f;
  if (fi < 32) {                                    // Bd: nt(4) x ks(8)
    const int nt = fi >> 3, ks = fi & 7;
    #pragma unroll
    for (int j = 0; j < 8; ++j) f[j] = f2bf(Wd[(ks*32 + (l>>4)*8 + j)*64 + nt*16 + (l&15)]);
  } else if (fi < 48) {                             // Bc: nt(8) x ks(2)
    const int idx = fi - 32, nt = idx >> 1, ks = idx & 1;
    const int col = nt*16 + (l&15), cw = col>>6, co = col&63;
    #pragma unroll
    for (int j = 0; j < 8; ++j) f[j] = f2bf(Wc[co*128 + cw*64 + ks*32 + (l>>4)*8 + j]);
  } else {                                          // Ba: nt(16) x ks(2)
    const int idx = fi - 48, nt = idx >> 1, ks = idx & 1;
    const int col = nt*16 + (l&15);
    #pragma unroll
    for (int j = 0; j < 8; ++j) f[j] = f2bf(Wa[(ks*32 + (l>>4)*8 + j)*256 + col]);
  }
  wsf[e] = f;
}

template<bool USE_WS>
__global__ __launch_bounds__(256, 5)
void fused_gnn_v14(const float* __restrict__ x,
                   const float* __restrict__ Wd, const float* __restrict__ bd,
                   const float* __restrict__ bn1s, const float* __restrict__ bn1b,
                   const float* __restrict__ bn1m, const float* __restrict__ bn1v,
                   const float* __restrict__ Wc,
                   const float* __restrict__ bn2s, const float* __restrict__ bn2b,
                   const float* __restrict__ bn2m, const float* __restrict__ bn2v,
                   const float* __restrict__ Wa, const float* __restrict__ ba,
                   const bf16x8* __restrict__ wsf,
                   float* __restrict__ out)
{
  // ~19.8 KB static LDS
  __shared__ short xbf[18*XBSTR];
  __shared__ __align__(16) char uni_raw[3072];      // union: xdT bf16[64][24] | att bf16[5][260]
  __shared__ float mw[5*MWC];
  __shared__ short mbf[16*MSTR];
  __shared__ short abf[16*MSTR];

  short* xdT = (short*)uni_raw;
  short* att = (short*)uni_raw;

  const int tid  = threadIdx.x;
  const int l    = tid & 63;
  const int wv   = tid >> 6;
  const int arow = l & 15;
  const int ak8  = (l >> 4) * 8;
  const int b0   = blockIdx.x * 2;      // two sequential batches
  const int colA = wv*16 + arow;
  const int c4   = l*4;
  const int r0   = tid >> 6;

  const float a1r = bn1s[colA] * rsqrtf(bn1v[colA] + 1e-5f);
  const float b1r = (bd[colA] - bn1m[colA])*a1r + bn1b[colA];
  const float a2r = bn2s[l] * rsqrtf(bn2v[l] + 1e-5f);
  const float b2r = bn2b[l] - bn2m[l]*a2r;

  auto store4 = [&](v4f v, int r){
    uint2 u; u.x = f2bf2(v.x, v.y); u.y = f2bf2(v.z, v.w);
    *(uint2*)&xbf[r*XBSTR + c4] = u;
  };

  // ---- phase lambdas (operate on LDS + per-lane regs; identical both batches) ----
  auto phaseA = [&](){
    f32x4 acc0 = {0.f,0.f,0.f,0.f};
    f32x4 acc1 = {0.f,0.f,0.f,0.f};
    const int rowT = (arow == 0) ? 16 : 17;
    #pragma unroll
    for (int h = 0; h < 2; ++h) {
      bf16x8 Bd0 = get_bd<USE_WS>(wsf, Wd, wv, h*4 + 0, l);
      bf16x8 Bd1 = get_bd<USE_WS>(wsf, Wd, wv, h*4 + 1, l);
      bf16x8 Bd2 = get_bd<USE_WS>(wsf, Wd, wv, h*4 + 2, l);
      bf16x8 Bd3 = get_bd<USE_WS>(wsf, Wd, wv, h*4 + 3, l);
      #pragma unroll
      for (int k4 = 0; k4 < 4; ++k4) {
        const int ks = h*4 + k4;
        const bf16x8 Bd = (k4==0)?Bd0:(k4==1)?Bd1:(k4==2)?Bd2:Bd3;
        bf16x8 a0 = *(const bf16x8*)&xbf[arow*XBSTR + ks*32 + ak8];
        acc0 = __builtin_amdgcn_mfma_f32_16x16x32_bf16(a0, Bd, acc0, 0, 0, 0);
        bf16x8 a1 = *(const bf16x8*)&xbf[rowT*XBSTR + ks*32 + ak8];
        acc1 = __builtin_amdgcn_mfma_f32_16x16x32_bf16(a1, Bd, acc1, 0, 0, 0);
      }
    }
    const float s0 = fsilu(acc0[0]*a1r + b1r);
    const float s1 = fsilu(acc0[1]*a1r + b1r);
    const float s2 = fsilu(acc0[2]*a1r + b1r);
    const float s3 = fsilu(acc0[3]*a1r + b1r);
    uint2 u; u.x = f2bf2(s0, s1); u.y = f2bf2(s2, s3);
    *(uint2*)&xdT[colA*XDT + (l>>4)*4] = u;
    if ((l >> 4) == 0)
      xdT[colA*XDT + 16] = f2bf(fsilu(acc1[0]*a1r + b1r));
  };

  auto phaseB1 = [&](){
    const int i = l;
    #define XDV(r) bf2f(xdT[i*XDT + (r)])
    if (wv == 0) {
      mbf[0*MSTR + i] = f2bf((XDV(0)+XDV(1)+XDV(2)+XDV(3)+XDV(4))*0.2f);
      mbf[4*MSTR + i] = f2bf((XDV(12)+XDV(14)+XDV(16))*(1.f/3.f));
    } else if (wv == 1) {
      mbf[1*MSTR + i] = f2bf((XDV(5)+XDV(7)+XDV(9))*(1.f/3.f));
    } else if (wv == 2) {
      mbf[2*MSTR + i] = f2bf((XDV(6)+XDV(8)+XDV(10))*(1.f/3.f));
    } else {
      mbf[3*MSTR + i] = f2bf((XDV(11)+XDV(13)+XDV(15))*(1.f/3.f));
    }
    #undef XDV
  };

  auto phaseB2 = [&](){
    bf16x8 am0 = *(const bf16x8*)&mbf[arow*MSTR + 0*32 + ak8];
    bf16x8 am1 = *(const bf16x8*)&mbf[arow*MSTR + 1*32 + ak8];
    #pragma unroll
    for (int t = 0; t < 2; ++t) {
      const int nt = wv*2 + t;
      f32x4 acc = {0.f,0.f,0.f,0.f};
      acc = __builtin_amdgcn_mfma_f32_16x16x32_bf16(am0, get_bc<USE_WS>(wsf, Wc, nt, 0, l), acc, 0, 0, 0);
      acc = __builtin_amdgcn_mfma_f32_16x16x32_bf16(am1, get_bc<USE_WS>(wsf, Wc, nt, 1, l), acc, 0, 0, 0);
      if ((l >> 4) == 0) {
        #pragma unroll
        for (int j = 0; j < 4; ++j) mw[j*MWC + nt*16 + arow] = acc[j];
      } else if ((l >> 4) == 1) {
        mw[4*MWC + nt*16 + arow] = acc[0];
      }
    }
  };

  auto phaseB3 = [&](){
    const int o = l;
    float m2c0 = mw[0*MWC + 64 + o], m2c1 = mw[1*MWC + 64 + o];
    float m2c2 = mw[2*MWC + 64 + o], m2c3 = mw[3*MWC + 64 + o];
    float m2c4 = mw[4*MWC + 64 + o];
    auto doG = [&](int g, float m2g){
      const float bse = mw[g*MWC + o] - m2g;
      float s = 0.f;
      if (g != 0) s += fsilu((bse + m2c0)*a2r + b2r);
      if (g != 1) s += fsilu((bse + m2c1)*a2r + b2r);
      if (g != 2) s += fsilu((bse + m2c2)*a2r + b2r);
      if (g != 3) s += fsilu((bse + m2c3)*a2r + b2r);
      if (g != 4) s += fsilu((bse + m2c4)*a2r + b2r);
      abf[g*MSTR + o] = f2bf(s);
    };
    if (wv == 0) { doG(0, m2c0); doG(4, m2c4); }
    else if (wv == 1) doG(1, m2c1);
    else if (wv == 2) doG(2, m2c2);
    else doG(3, m2c3);
  };

  auto phaseE = [&](){
    bf16x8 ae0 = *(const bf16x8*)&abf[arow*MSTR + 0*32 + ak8];
    bf16x8 ae1 = *(const bf16x8*)&abf[arow*MSTR + 1*32 + ak8];
    #pragma unroll
    for (int t = 0; t < 4; ++t) {
      const int nt = wv*4 + t;
      const int colE = nt*16 + arow;
      f32x4 acc = {0.f,0.f,0.f,0.f};
      acc = __builtin_amdgcn_mfma_f32_16x16x32_bf16(ae0, get_ba<USE_WS>(wsf, Wa, nt, 0, l), acc, 0, 0, 0);
      acc = __builtin_amdgcn_mfma_f32_16x16x32_bf16(ae1, get_ba<USE_WS>(wsf, Wa, nt, 1, l), acc, 0, 0, 0);
      const float bav = ba[colE];
      const int q4 = l >> 4;
      if (q4 == 0) {
        #pragma unroll
        for (int j = 0; j < 4; ++j)
          att[j*ATS + colE] = f2bf(fsigm(acc[j] + bav));
      } else if (q4 == 1) {
        att[4*ATS + colE] = f2bf(fsigm(acc[0] + bav));
      }
    }
  };

  auto phaseF = [&](v4f f0, v4f f1, v4f f2, v4f f3, v4f f4, int b){
    float* og = out + (size_t)b*4352;
    constexpr int GOF[17] = {0,0,0,0,0,1,2,1,2,1,2,3,4,3,4,3,4};
    auto emit = [&](v4f xv, int k){
      const bf16x4 a4 = *(const bf16x4*)&att[GOF[k]*ATS + c4];
      v4f o;
      o.x = xv.x * bf2f(a4[0]);
      o.y = xv.y * bf2f(a4[1]);
      o.z = xv.z * bf2f(a4[2]);
      o.w = xv.w * bf2f(a4[3]);
      *(v4f*)&og[k*256 + c4] = o;
    };
    emit(f0, r0);      emit(f1, r0 + 4);
    emit(f2, r0 + 8);  emit(f3, r0 + 12);
    if (tid < 64) emit(f4, 16);
  };

  // ================= batch 0 =================
  v4f a0, a1, a2, a3, a4;                // batch-0 x (f32, reused by F0)
  {
    const v4f* x4 = (const v4f*)(x + (size_t)b0 * 4352);
    a0 = x4[tid];        a1 = x4[256 + tid];
    a2 = x4[512 + tid];  a3 = x4[768 + tid];
    if (tid < 64) a4 = x4[1024 + tid];
    store4(a0, r0);      store4(a1, r0 + 4);
    store4(a2, r0 + 8);  store4(a3, r0 + 12);
    if (tid < 64) store4(a4, 16);
  }
  __syncthreads();                                   // bar1

  phaseA();
  __syncthreads();                                   // bar2 (xbf dead for batch 0)

  // issue batch-1 x loads now; latency hides under B1..E
  v4f c0, c1, c2, c3, c4r;
  {
    const v4f* y4 = (const v4f*)(x + (size_t)(b0+1) * 4352);
    c0 = y4[tid];        c1 = y4[256 + tid];
    c2 = y4[512 + tid];  c3 = y4[768 + tid];
    if (tid < 64) c4r = y4[1024 + tid];
  }

  phaseB1();
  __syncthreads();                                   // bar3
  phaseB2();
  __syncthreads();                                   // bar4
  phaseB3();
  __syncthreads();                                   // bar5
  phaseE();
  __syncthreads();                                   // bar6
  phaseF(a0, a1, a2, a3, a4, b0);                    // reads att + regs (not xbf)
  // stage batch-1 into xbf (xbf unread since bar2; F doesn't touch it)
  store4(c0, r0);      store4(c1, r0 + 4);
  store4(c2, r0 + 8);  store4(c3, r0 + 12);
  if (tid < 64) store4(c4r, 16);
  __syncthreads();                                   // bar7: staging+att-reads -> batch-1 A

  // ================= batch 1 =================
  phaseA();
  __syncthreads();
  phaseB1();
  __syncthreads();
  phaseB2();
  __syncthreads();
  phaseB3();
  __syncthreads();
  phaseE();
  __syncthreads();
  phaseF(c0, c1, c2, c3, c4r, b0 + 1);
}

extern "C" void kernel_launch(void* const* d_in, const int* in_sizes, int n_in,
                              void* d_out, int out_size, void* d_ws, size_t ws_size,
                              hipStream_t stream) {
    (void)n_in; (void)out_size;
    const float* x   = (const float*)d_in[0];
    const float* Wd  = (const float*)d_in[1];
    const float* bd  = (const float*)d_in[2];
    const float* s1  = (const float*)d_in[3];
    const float* b1  = (const float*)d_in[4];
    const float* m1  = (const float*)d_in[5];
    const float* v1  = (const float*)d_in[6];
    const float* Wc  = (const float*)d_in[7];
    const float* s2  = (const float*)d_in[8];
    const float* b2  = (const float*)d_in[9];
    const float* m2  = (const float*)d_in[10];
    const float* v2  = (const float*)d_in[11];
    const float* Wa  = (const float*)d_in[12];
    const float* ba  = (const float*)d_in[13];

    const int Btot = in_sizes[0] / (17 * 256);   // 4096
    const int GRID = Btot / 2;                   // 2048 blocks, 2 batches each
    bf16x8* wsf = (bf16x8*)d_ws;

    if (ws_size >= (size_t)FRAG_SLOTS * 16) {
        pack_frags<<<FRAG_SLOTS/256, 256, 0, stream>>>(Wd, Wc, Wa, wsf);
        fused_gnn_v14<true><<<GRID, 256, 0, stream>>>(
            x, Wd, bd, s1, b1, m1, v1, Wc, s2, b2, m2, v2, Wa, ba,
            wsf, (float*)d_out);
    } else {
        fused_gnn_v14<false><<<GRID, 256, 0, stream>>>(
            x, Wd, bd, s1, b1, m1, v1, Wc, s2, b2, m2, v2, Wa, ba,
            wsf, (float*)d_out);
    }
}

// Round 17
// 74.123 us; speedup vs baseline: 1.8851x; 1.1813x over previous
//
#include <hip/hip_runtime.h>

typedef float  v4f    __attribute__((ext_vector_type(4)));
typedef float  f32x4  __attribute__((ext_vector_type(4)));
typedef short  bf16x8 __attribute__((ext_vector_type(8)));
typedef short  bf16x4 __attribute__((ext_vector_type(4)));

namespace {
constexpr int XBSTR = 264;   // xbf row stride (shorts)
constexpr int XDT   = 24;    // xdT row stride (shorts); 48 B, b128-aligned
constexpr int MWC   = 129;   // mw row stride (f32)
constexpr int ATS   = 260;   // att row stride (shorts); 8B-aligned rows
constexpr int MSTR  = 72;    // mbf/abf row stride (shorts)
constexpr int NB    = 4;     // batches per block (sequential loop)
constexpr int FRAG_SLOTS = 5120;

__device__ __forceinline__ float fsilu(float v){ return v/(1.f+__expf(-v)); }
__device__ __forceinline__ float fsigm(float v){ return 1.f/(1.f+__expf(-v)); }

__device__ __forceinline__ unsigned f2bf2(float a, float b){
  unsigned r;
  asm("v_cvt_pk_bf16_f32 %0, %1, %2" : "=v"(r) : "v"(a), "v"(b));
  return r;
}
__device__ __forceinline__ short f2bf(float f){   // scalar RNE, matches cvt_pk
  unsigned u = __builtin_bit_cast(unsigned, f);
  return (short)((u + 0x7FFFu + ((u>>16)&1u)) >> 16);
}
__device__ __forceinline__ float bf2f(short s){
  unsigned u = ((unsigned)(unsigned short)s) << 16;
  return __builtin_bit_cast(float, u);
}

template<bool USE_WS>
__device__ __forceinline__ bf16x8 get_bd(const bf16x8* wsf, const float* Wd,
                                         int nt, int ks, int l){
  if constexpr (USE_WS) return wsf[(nt*8 + ks)*64 + l];
  bf16x8 f;
  #pragma unroll
  for (int j = 0; j < 8; ++j) f[j] = f2bf(Wd[(ks*32 + (l>>4)*8 + j)*64 + nt*16 + (l&15)]);
  return f;
}
template<bool USE_WS>
__device__ __forceinline__ bf16x8 get_bc(const bf16x8* wsf, const float* Wc,
                                         int nt, int ks, int l){
  if constexpr (USE_WS) return wsf[2048 + (nt*2 + ks)*64 + l];
  const int col = nt*16 + (l&15), cw = col>>6, co = col&63;
  bf16x8 f;
  #pragma unroll
  for (int j = 0; j < 8; ++j) f[j] = f2bf(Wc[co*128 + cw*64 + ks*32 + (l>>4)*8 + j]);
  return f;
}
template<bool USE_WS>
__device__ __forceinline__ bf16x8 get_ba(const bf16x8* wsf, const float* Wa,
                                         int nt, int ks, int l){
  if constexpr (USE_WS) return wsf[3072 + (nt*2 + ks)*64 + l];
  const int col = nt*16 + (l&15);
  bf16x8 f;
  #pragma unroll
  for (int j = 0; j < 8; ++j) f[j] = f2bf(Wa[(ks*32 + (l>>4)*8 + j)*256 + col]);
  return f;
}
}

__global__ __launch_bounds__(256)
void pack_frags(const float* __restrict__ Wd, const float* __restrict__ Wc,
                const float* __restrict__ Wa, bf16x8* __restrict__ wsf)
{
  const int e  = blockIdx.x*256 + threadIdx.x;      // 0..5119
  const int l  = e & 63;
  const int fi = e >> 6;                            // 0..79
  bf16x8 f;
  if (fi < 32) {                                    // Bd: nt(4) x ks(8)
    const int nt = fi >> 3, ks = fi & 7;
    #pragma unroll
    for (int j = 0; j < 8; ++j) f[j] = f2bf(Wd[(ks*32 + (l>>4)*8 + j)*64 + nt*16 + (l&15)]);
  } else if (fi < 48) {                             // Bc: nt(8) x ks(2)
    const int idx = fi - 32, nt = idx >> 1, ks = idx & 1;
    const int col = nt*16 + (l&15), cw = col>>6, co = col&63;
    #pragma unroll
    for (int j = 0; j < 8; ++j) f[j] = f2bf(Wc[co*128 + cw*64 + ks*32 + (l>>4)*8 + j]);
  } else {                                          // Ba: nt(16) x ks(2)
    const int idx = fi - 48, nt = idx >> 1, ks = idx & 1;
    const int col = nt*16 + (l&15);
    #pragma unroll
    for (int j = 0; j < 8; ++j) f[j] = f2bf(Wa[(ks*32 + (l>>4)*8 + j)*256 + col]);
  }
  wsf[e] = f;
}

template<bool USE_WS>
__global__ __launch_bounds__(256, 6)
void fused_gnn_v15(const float* __restrict__ x,
                   const float* __restrict__ Wd, const float* __restrict__ bd,
                   const float* __restrict__ bn1s, const float* __restrict__ bn1b,
                   const float* __restrict__ bn1m, const float* __restrict__ bn1v,
                   const float* __restrict__ Wc,
                   const float* __restrict__ bn2s, const float* __restrict__ bn2b,
                   const float* __restrict__ bn2m, const float* __restrict__ bn2v,
                   const float* __restrict__ Wa, const float* __restrict__ ba,
                   const bf16x8* __restrict__ wsf,
                   float* __restrict__ out)
{
  // ~19.8 KB static LDS -> 8 blocks/CU possible; grid sized for 4/CU
  __shared__ short xbf[18*XBSTR];                   // row 17 = tail-clamp garbage target
  __shared__ __align__(16) char uni_raw[3072];      // union: xdT bf16[64][24] | att bf16[5][260]
  __shared__ float mw[5*MWC];
  __shared__ short mbf[16*MSTR];                    // rows 5-15 garbage
  __shared__ short abf[16*MSTR];

  short* xdT = (short*)uni_raw;
  short* att = (short*)uni_raw;

  const int tid  = threadIdx.x;
  const int l    = tid & 63;
  const int wv   = tid >> 6;            // wave 0..3
  const int arow = l & 15;
  const int ak8  = (l >> 4) * 8;
  const int colA = wv*16 + arow;
  const int c4   = l*4;                 // column quad owned in stage/F mapping
  const int r0   = tid >> 6;            // base row owned in stage/F mapping

  // ---- per-lane BN affines in registers (b_down folded into bn1 bias) ----
  const float a1r = bn1s[colA] * rsqrtf(bn1v[colA] + 1e-5f);
  const float b1r = (bd[colA] - bn1m[colA])*a1r + bn1b[colA];
  const float a2r = bn2s[l] * rsqrtf(bn2v[l] + 1e-5f);
  const float b2r = bn2b[l] - bn2m[l]*a2r;

  for (int it = 0; it < NB; ++it) {
    const int b = blockIdx.x * NB + it;

    // ---- stage x -> bf16 LDS (regs die immediately; no cross-barrier state) ----
    {
      const v4f* x4 = (const v4f*)(x + (size_t)b * 4352);
      auto ldst = [&](int slot, int r){
        const v4f v = x4[slot*256 + tid];
        uint2 u; u.x = f2bf2(v.x, v.y); u.y = f2bf2(v.z, v.w);
        *(uint2*)&xbf[r*XBSTR + c4] = u;
      };
      ldst(0, r0);      ldst(1, r0 + 4);
      ldst(2, r0 + 8);  ldst(3, r0 + 12);
      if (tid < 64) {
        const v4f v = x4[1024 + tid];
        uint2 u; u.x = f2bf2(v.x, v.y); u.y = f2bf2(v.z, v.w);
        *(uint2*)&xbf[16*XBSTR + c4] = u;
      }
    }
    __syncthreads();                                 // bar1: stage -> A

    // ---- Phase A (MFMA): xd = silu(bn1(x @ Wd)), M=17, N=64, K=256; -> xdT ----
    {
      f32x4 acc0 = {0.f,0.f,0.f,0.f};
      f32x4 acc1 = {0.f,0.f,0.f,0.f};
      const int rowT = (arow == 0) ? 16 : 17;
      #pragma unroll
      for (int h = 0; h < 2; ++h) {
        bf16x8 Bd[4];
        #pragma unroll
        for (int k4 = 0; k4 < 4; ++k4) Bd[k4] = get_bd<USE_WS>(wsf, Wd, wv, h*4 + k4, l);
        #pragma unroll
        for (int k4 = 0; k4 < 4; ++k4) {
          const int ks = h*4 + k4;
          bf16x8 a0 = *(const bf16x8*)&xbf[arow*XBSTR + ks*32 + ak8];
          acc0 = __builtin_amdgcn_mfma_f32_16x16x32_bf16(a0, Bd[k4], acc0, 0, 0, 0);
          bf16x8 a1 = *(const bf16x8*)&xbf[rowT*XBSTR + ks*32 + ak8];
          acc1 = __builtin_amdgcn_mfma_f32_16x16x32_bf16(a1, Bd[k4], acc1, 0, 0, 0);
        }
      }
      const float s0 = fsilu(acc0[0]*a1r + b1r);
      const float s1 = fsilu(acc0[1]*a1r + b1r);
      const float s2 = fsilu(acc0[2]*a1r + b1r);
      const float s3 = fsilu(acc0[3]*a1r + b1r);
      uint2 u; u.x = f2bf2(s0, s1); u.y = f2bf2(s2, s3);
      *(uint2*)&xdT[colA*XDT + (l>>4)*4] = u;
      if ((l >> 4) == 0)
        xdT[colA*XDT + 16] = f2bf(fsilu(acc1[0]*a1r + b1r));
    }
    __syncthreads();                                 // bar2: A -> B1 (xdT cross-wave)

    // ---- prefetch B2 weight frags (latency covered by B1 + bar3) ----
    bf16x8 BcT[2][2];
    #pragma unroll
    for (int t = 0; t < 2; ++t)
      #pragma unroll
      for (int ks = 0; ks < 2; ++ks)
        BcT[t][ks] = get_bc<USE_WS>(wsf, Wc, wv*2 + t, ks, l);

    // ---- Phase B1 (split): wave wv computes group g=wv; wave 0 also g=4 ----
    {
      const int i = l;
      #define XDV(r) bf2f(xdT[i*XDT + (r)])
      if (wv == 0) {
        mbf[0*MSTR + i] = f2bf((XDV(0)+XDV(1)+XDV(2)+XDV(3)+XDV(4))*0.2f);
        mbf[4*MSTR + i] = f2bf((XDV(12)+XDV(14)+XDV(16))*(1.f/3.f));
      } else if (wv == 1) {
        mbf[1*MSTR + i] = f2bf((XDV(5)+XDV(7)+XDV(9))*(1.f/3.f));
      } else if (wv == 2) {
        mbf[2*MSTR + i] = f2bf((XDV(6)+XDV(8)+XDV(10))*(1.f/3.f));
      } else {
        mbf[3*MSTR + i] = f2bf((XDV(11)+XDV(13)+XDV(15))*(1.f/3.f));
      }
      #undef XDV
    }
    __syncthreads();                                 // bar3: B1 -> B2 (mbf cross-wave)

    // ---- Phase B2 (MFMA): mw = means @ [Wc1|Wc2], M=5, N=128 ----
    {
      bf16x8 am[2];
      #pragma unroll
      for (int ks = 0; ks < 2; ++ks)
        am[ks] = *(const bf16x8*)&mbf[arow*MSTR + ks*32 + ak8];
      #pragma unroll
      for (int t = 0; t < 2; ++t) {
        const int nt = wv*2 + t;
        f32x4 acc = {0.f,0.f,0.f,0.f};
        #pragma unroll
        for (int ks = 0; ks < 2; ++ks)
          acc = __builtin_amdgcn_mfma_f32_16x16x32_bf16(am[ks], BcT[t][ks], acc, 0, 0, 0);
        if ((l >> 4) == 0) {
          #pragma unroll
          for (int j = 0; j < 4; ++j) mw[j*MWC + nt*16 + arow] = acc[j];
        } else if ((l >> 4) == 1) {
          mw[4*MWC + nt*16 + arow] = acc[0];
        }
      }
    }
    __syncthreads();                                 // bar4: B2 -> B3 (mw cross-wave)

    // ---- prefetch phase-E weight frags (latency covered by B3 + bar5) ----
    bf16x8 BaT[4][2];
    #pragma unroll
    for (int t = 0; t < 4; ++t)
      #pragma unroll
      for (int ks = 0; ks < 2; ++ks)
        BaT[t][ks] = get_ba<USE_WS>(wsf, Wa, wv*4 + t, ks, l);

    // ---- Phase B3 (split): wave wv computes g=wv; wave 0 also g=4 ----
    {
      const int o = l;
      float m2c[5];
      #pragma unroll
      for (int cc = 0; cc < 5; ++cc) m2c[cc] = mw[cc*MWC + 64 + o];
      auto doG = [&](int g){
        const float bse = mw[g*MWC + o] - m2c[g];
        float s = 0.f;
        #pragma unroll
        for (int cc = 0; cc < 5; ++cc) {
          if (cc != g) s += fsilu((bse + m2c[cc])*a2r + b2r);
        }
        abf[g*MSTR + o] = f2bf(s);
      };
      if (wv == 0) { doG(0); doG(4); }
      else if (wv == 1) doG(1);
      else if (wv == 2) doG(2);
      else doG(3);
    }
    __syncthreads();                                 // bar5: B3 -> E (abf cross-wave)

    // ---- Phase E (MFMA): att = sigmoid(agg @ Wa + ba); sigmoid only where g<5 ----
    {
      bf16x8 ae[2];
      #pragma unroll
      for (int ks = 0; ks < 2; ++ks)
        ae[ks] = *(const bf16x8*)&abf[arow*MSTR + ks*32 + ak8];
      #pragma unroll
      for (int t = 0; t < 4; ++t) {
        const int nt = wv*4 + t;
        const int colE = nt*16 + arow;
        f32x4 acc = {0.f,0.f,0.f,0.f};
        #pragma unroll
        for (int ks = 0; ks < 2; ++ks)
          acc = __builtin_amdgcn_mfma_f32_16x16x32_bf16(ae[ks], BaT[t][ks], acc, 0, 0, 0);
        const float bav = ba[colE];
        const int q4 = l >> 4;
        if (q4 == 0) {
          #pragma unroll
          for (int j = 0; j < 4; ++j)
            att[j*ATS + colE] = f2bf(fsigm(acc[j] + bav));
        } else if (q4 == 1) {
          att[4*ATS + colE] = f2bf(fsigm(acc[0] + bav));
        }
      }
    }
    __syncthreads();                                 // bar6: E -> F (att cross-wave)

    // ---- Phase F: out = bf16(x)[xbf] * att, b64 LDS reads + dwordx4 stores ----
    {
      float* og = out + (size_t)b*4352;
      constexpr int GOF[17] = {0,0,0,0,0,1,2,1,2,1,2,3,4,3,4,3,4};
      auto emit = [&](int k){
        const bf16x4 xv4 = *(const bf16x4*)&xbf[k*XBSTR + c4];
        const bf16x4 a4  = *(const bf16x4*)&att[GOF[k]*ATS + c4];
        v4f o;
        o.x = bf2f(xv4[0]) * bf2f(a4[0]);
        o.y = bf2f(xv4[1]) * bf2f(a4[1]);
        o.z = bf2f(xv4[2]) * bf2f(a4[2]);
        o.w = bf2f(xv4[3]) * bf2f(a4[3]);
        *(v4f*)&og[k*256 + c4] = o;
      };
      emit(r0);      emit(r0 + 4);
      emit(r0 + 8);  emit(r0 + 12);
      if (tid < 64) emit(16);
    }
    __syncthreads();                                 // bar7: F reads -> next iter staging
  }
}

extern "C" void kernel_launch(void* const* d_in, const int* in_sizes, int n_in,
                              void* d_out, int out_size, void* d_ws, size_t ws_size,
                              hipStream_t stream) {
    (void)n_in; (void)out_size;
    const float* x   = (const float*)d_in[0];
    const float* Wd  = (const float*)d_in[1];
    const float* bd  = (const float*)d_in[2];
    const float* s1  = (const float*)d_in[3];
    const float* b1  = (const float*)d_in[4];
    const float* m1  = (const float*)d_in[5];
    const float* v1  = (const float*)d_in[6];
    const float* Wc  = (const float*)d_in[7];
    const float* s2  = (const float*)d_in[8];
    const float* b2  = (const float*)d_in[9];
    const float* m2  = (const float*)d_in[10];
    const float* v2  = (const float*)d_in[11];
    const float* Wa  = (const float*)d_in[12];
    const float* ba  = (const float*)d_in[13];

    const int Btot = in_sizes[0] / (17 * 256);   // 4096
    const int GRID = Btot / NB;                  // 1024 blocks -> 4/CU resident
    bf16x8* wsf = (bf16x8*)d_ws;

    if (ws_size >= (size_t)FRAG_SLOTS * 16) {
        pack_frags<<<FRAG_SLOTS/256, 256, 0, stream>>>(Wd, Wc, Wa, wsf);
        fused_gnn_v15<true><<<GRID, 256, 0, stream>>>(
            x, Wd, bd, s1, b1, m1, v1, Wc, s2, b2, m2, v2, Wa, ba,
            wsf, (float*)d_out);
    } else {
        fused_gnn_v15<false><<<GRID, 256, 0, stream>>>(
            x, Wd, bd, s1, b1, m1, v1, Wc, s2, b2, m2, v2, Wa, ba,
            wsf, (float*)d_out);
    }
}

// Round 18
// 67.756 us; speedup vs baseline: 2.0622x; 1.0940x over previous
//
#include <hip/hip_runtime.h>

typedef float  v4f    __attribute__((ext_vector_type(4)));
typedef float  f32x4  __attribute__((ext_vector_type(4)));
typedef short  bf16x8 __attribute__((ext_vector_type(8)));
typedef short  bf16x4 __attribute__((ext_vector_type(4)));

namespace {
constexpr int XBSTR = 264;   // xbf row stride (shorts)
constexpr int XDT   = 24;    // xdT row stride (shorts); 48 B, b128-aligned
constexpr int MWC   = 129;   // mw row stride (f32)
constexpr int ATS   = 260;   // att row stride (shorts); 8B-aligned rows
constexpr int MSTR  = 72;    // mbf/abf row stride (shorts)
constexpr int FRAG_SLOTS = 5120;

__device__ __forceinline__ float fsilu(float v){ return v/(1.f+__expf(-v)); }
__device__ __forceinline__ float fsigm(float v){ return 1.f/(1.f+__expf(-v)); }

__device__ __forceinline__ unsigned f2bf2(float a, float b){
  unsigned r;
  asm("v_cvt_pk_bf16_f32 %0, %1, %2" : "=v"(r) : "v"(a), "v"(b));
  return r;
}
__device__ __forceinline__ short f2bf(float f){   // scalar RNE, matches cvt_pk
  unsigned u = __builtin_bit_cast(unsigned, f);
  return (short)((u + 0x7FFFu + ((u>>16)&1u)) >> 16);
}
__device__ __forceinline__ float bf2f(short s){
  unsigned u = ((unsigned)(unsigned short)s) << 16;
  return __builtin_bit_cast(float, u);
}

template<bool USE_WS>
__device__ __forceinline__ bf16x8 get_bd(const bf16x8* wsf, const float* Wd,
                                         int nt, int ks, int l){
  if constexpr (USE_WS) return wsf[(nt*8 + ks)*64 + l];
  bf16x8 f;
  #pragma unroll
  for (int j = 0; j < 8; ++j) f[j] = f2bf(Wd[(ks*32 + (l>>4)*8 + j)*64 + nt*16 + (l&15)]);
  return f;
}
template<bool USE_WS>
__device__ __forceinline__ bf16x8 get_bc(const bf16x8* wsf, const float* Wc,
                                         int nt, int ks, int l){
  if constexpr (USE_WS) return wsf[2048 + (nt*2 + ks)*64 + l];
  const int col = nt*16 + (l&15), cw = col>>6, co = col&63;
  bf16x8 f;
  #pragma unroll
  for (int j = 0; j < 8; ++j) f[j] = f2bf(Wc[co*128 + cw*64 + ks*32 + (l>>4)*8 + j]);
  return f;
}
template<bool USE_WS>
__device__ __forceinline__ bf16x8 get_ba(const bf16x8* wsf, const float* Wa,
                                         int nt, int ks, int l){
  if constexpr (USE_WS) return wsf[3072 + (nt*2 + ks)*64 + l];
  const int col = nt*16 + (l&15);
  bf16x8 f;
  #pragma unroll
  for (int j = 0; j < 8; ++j) f[j] = f2bf(Wa[(ks*32 + (l>>4)*8 + j)*256 + col]);
  return f;
}
}

__global__ __launch_bounds__(256)
void pack_frags(const float* __restrict__ Wd, const float* __restrict__ Wc,
                const float* __restrict__ Wa, bf16x8* __restrict__ wsf)
{
  const int e  = blockIdx.x*256 + threadIdx.x;      // 0..5119
  const int l  = e & 63;
  const int fi = e >> 6;                            // 0..79
  bf16x8 f;
  if (fi < 32) {                                    // Bd: nt(4) x ks(8)
    const int nt = fi >> 3, ks = fi & 7;
    #pragma unroll
    for (int j = 0; j < 8; ++j) f[j] = f2bf(Wd[(ks*32 + (l>>4)*8 + j)*64 + nt*16 + (l&15)]);
  } else if (fi < 48) {                             // Bc: nt(8) x ks(2)
    const int idx = fi - 32, nt = idx >> 1, ks = idx & 1;
    const int col = nt*16 + (l&15), cw = col>>6, co = col&63;
    #pragma unroll
    for (int j = 0; j < 8; ++j) f[j] = f2bf(Wc[co*128 + cw*64 + ks*32 + (l>>4)*8 + j]);
  } else {                                          // Ba: nt(16) x ks(2)
    const int idx = fi - 48, nt = idx >> 1, ks = idx & 1;
    const int col = nt*16 + (l&15);
    #pragma unroll
    for (int j = 0; j < 8; ++j) f[j] = f2bf(Wa[(ks*32 + (l>>4)*8 + j)*256 + col]);
  }
  wsf[e] = f;
}

template<bool USE_WS>
__global__ __launch_bounds__(256, 5)
void fused_gnn_v16(const float* __restrict__ x,
                   const float* __restrict__ Wd, const float* __restrict__ bd,
                   const float* __restrict__ bn1s, const float* __restrict__ bn1b,
                   const float* __restrict__ bn1m, const float* __restrict__ bn1v,
                   const float* __restrict__ Wc,
                   const float* __restrict__ bn2s, const float* __restrict__ bn2b,
                   const float* __restrict__ bn2m, const float* __restrict__ bn2v,
                   const float* __restrict__ Wa, const float* __restrict__ ba,
                   const bf16x8* __restrict__ wsf,
                   float* __restrict__ out)
{
  // ~19.8 KB static LDS
  __shared__ short xbf[18*XBSTR];                   // row 17 = tail-clamp garbage target
  __shared__ __align__(16) char uni_raw[3072];      // union: xdT bf16[64][24] | att bf16[5][260]
  __shared__ float mw[5*MWC];
  __shared__ short mbf[16*MSTR];                    // rows 5-15 garbage (discarded MFMA rows)
  __shared__ short abf[16*MSTR];

  short* xdT = (short*)uni_raw;
  short* att = (short*)uni_raw;

  const int tid  = threadIdx.x;
  const int l    = tid & 63;
  const int wv   = tid >> 6;            // wave 0..3
  const int arow = l & 15;
  const int ak8  = (l >> 4) * 8;
  const int b    = blockIdx.x;          // one batch per block
  const int colA = wv*16 + arow;
  const int c4   = l*4;
  const int r0   = tid >> 6;
  const int midw = b & 3;               // which wave runs the middle section (SIMD spread)

  // ---- per-lane BN affines in registers (b_down folded into bn1 bias) ----
  const float a1r = bn1s[colA] * rsqrtf(bn1v[colA] + 1e-5f);
  const float b1r = (bd[colA] - bn1m[colA])*a1r + bn1b[colA];
  const float a2r = bn2s[l] * rsqrtf(bn2v[l] + 1e-5f);
  const float b2r = bn2b[l] - bn2m[l]*a2r;

  // ---- stage x -> bf16 LDS (regs die immediately) ----
  {
    const v4f* x4 = (const v4f*)(x + (size_t)b * 4352);
    auto ldst = [&](int slot, int r){
      const v4f v = x4[slot*256 + tid];
      uint2 u; u.x = f2bf2(v.x, v.y); u.y = f2bf2(v.z, v.w);
      *(uint2*)&xbf[r*XBSTR + c4] = u;
    };
    ldst(0, r0);      ldst(1, r0 + 4);
    ldst(2, r0 + 8);  ldst(3, r0 + 12);
    if (tid < 64) {
      const v4f v = x4[1024 + tid];
      uint2 u; u.x = f2bf2(v.x, v.y); u.y = f2bf2(v.z, v.w);
      *(uint2*)&xbf[16*XBSTR + c4] = u;
    }
  }
  __syncthreads();                                   // bar1: stage -> A

  // ---- Phase A (MFMA, all 4 waves): xd = silu(bn1(x @ Wd)); epilogue -> xdT ----
  {
    f32x4 acc0 = {0.f,0.f,0.f,0.f};
    f32x4 acc1 = {0.f,0.f,0.f,0.f};
    const int rowT = (arow == 0) ? 16 : 17;
    #pragma unroll
    for (int h = 0; h < 2; ++h) {
      bf16x8 Bd[4];
      #pragma unroll
      for (int k4 = 0; k4 < 4; ++k4) Bd[k4] = get_bd<USE_WS>(wsf, Wd, wv, h*4 + k4, l);
      #pragma unroll
      for (int k4 = 0; k4 < 4; ++k4) {
        const int ks = h*4 + k4;
        bf16x8 a0 = *(const bf16x8*)&xbf[arow*XBSTR + ks*32 + ak8];
        acc0 = __builtin_amdgcn_mfma_f32_16x16x32_bf16(a0, Bd[k4], acc0, 0, 0, 0);
        bf16x8 a1 = *(const bf16x8*)&xbf[rowT*XBSTR + ks*32 + ak8];
        acc1 = __builtin_amdgcn_mfma_f32_16x16x32_bf16(a1, Bd[k4], acc1, 0, 0, 0);
      }
    }
    const float s0 = fsilu(acc0[0]*a1r + b1r);
    const float s1 = fsilu(acc0[1]*a1r + b1r);
    const float s2 = fsilu(acc0[2]*a1r + b1r);
    const float s3 = fsilu(acc0[3]*a1r + b1r);
    uint2 u; u.x = f2bf2(s0, s1); u.y = f2bf2(s2, s3);
    *(uint2*)&xdT[colA*XDT + (l>>4)*4] = u;          // rows (l>>4)*4..+3 of column colA
    if ((l >> 4) == 0)
      xdT[colA*XDT + 16] = f2bf(fsilu(acc1[0]*a1r + b1r));
  }
  __syncthreads();                                   // bar2: A -> mid (xdT cross-wave)

  // ==== MIDDLE SECTION: single wave, zero barriers (in-wave LDS ordering) ====
  if (wv == midw) {
    // -- issue all 16 Bc frags (latency covered by B1 below) --
    bf16x8 Bc[8][2];
    #pragma unroll
    for (int t = 0; t < 8; ++t)
      #pragma unroll
      for (int ks = 0; ks < 2; ++ks)
        Bc[t][ks] = get_bc<USE_WS>(wsf, Wc, t, ks, l);

    // -- B1: lane l owns xdT column l; all 5 group means --
    {
      const bf16x8 rA = *(const bf16x8*)&xdT[l*XDT];       // rows 0-7
      const bf16x8 rB = *(const bf16x8*)&xdT[l*XDT + 8];   // rows 8-15
      const float x16v = bf2f(xdT[l*XDT + 16]);
      float xv[16];
      #pragma unroll
      for (int k = 0; k < 8; ++k) { xv[k] = bf2f(rA[k]); xv[k+8] = bf2f(rB[k]); }
      const float m0 = (xv[0]+xv[1]+xv[2]+xv[3]+xv[4])*0.2f;
      const float m1 = (xv[5]+xv[7]+xv[9])*(1.f/3.f);
      const float m2 = (xv[6]+xv[8]+xv[10])*(1.f/3.f);
      const float m3 = (xv[11]+xv[13]+xv[15])*(1.f/3.f);
      const float m4 = (xv[12]+xv[14]+x16v)*(1.f/3.f);
      const unsigned p01 = f2bf2(m0, m1);
      const unsigned p23 = f2bf2(m2, m3);
      mbf[0*MSTR + l] = (short)(p01 & 0xFFFFu);
      mbf[1*MSTR + l] = (short)(p01 >> 16);
      mbf[2*MSTR + l] = (short)(p23 & 0xFFFFu);
      mbf[3*MSTR + l] = (short)(p23 >> 16);
      mbf[4*MSTR + l] = f2bf(m4);
    }

    // -- B2: mw = means @ [Wc1|Wc2], all 8 n-tiles, in-wave --
    {
      bf16x8 am0 = *(const bf16x8*)&mbf[arow*MSTR + 0*32 + ak8];
      bf16x8 am1 = *(const bf16x8*)&mbf[arow*MSTR + 1*32 + ak8];
      #pragma unroll
      for (int t = 0; t < 8; ++t) {
        f32x4 acc = {0.f,0.f,0.f,0.f};
        acc = __builtin_amdgcn_mfma_f32_16x16x32_bf16(am0, Bc[t][0], acc, 0, 0, 0);
        acc = __builtin_amdgcn_mfma_f32_16x16x32_bf16(am1, Bc[t][1], acc, 0, 0, 0);
        if ((l >> 4) == 0) {
          #pragma unroll
          for (int j = 0; j < 4; ++j) mw[j*MWC + t*16 + arow] = acc[j];
        } else if ((l >> 4) == 1) {
          mw[4*MWC + t*16 + arow] = acc[0];
        }
      }
    }

    // -- issue Ba half 1 (nt 0..7; latency covered by B3) --
    bf16x8 Ba1[8][2];
    #pragma unroll
    for (int t = 0; t < 8; ++t)
      #pragma unroll
      for (int ks = 0; ks < 2; ++ks)
        Ba1[t][ks] = get_ba<USE_WS>(wsf, Wa, t, ks, l);

    // -- B3: agg at column o = l, all 5 groups --
    {
      const int o = l;
      float m2c[5];
      #pragma unroll
      for (int cc = 0; cc < 5; ++cc) m2c[cc] = mw[cc*MWC + 64 + o];
      #pragma unroll
      for (int g = 0; g < 5; ++g) {
        const float bse = mw[g*MWC + o] - m2c[g];
        float s = 0.f;
        #pragma unroll
        for (int cc = 0; cc < 5; ++cc) {
          if (cc != g) s += fsilu((bse + m2c[cc])*a2r + b2r);
        }
        abf[g*MSTR + o] = f2bf(s);
      }
    }

    // -- E: att = sigmoid(agg @ Wa + ba), 16 n-tiles, in-wave --
    {
      bf16x8 ae0 = *(const bf16x8*)&abf[arow*MSTR + 0*32 + ak8];
      bf16x8 ae1 = *(const bf16x8*)&abf[arow*MSTR + 1*32 + ak8];
      const int q4 = l >> 4;
      // half 1: nt 0..5 (Ba1), then issue half 2, then nt 6..7 + half 2
      #pragma unroll
      for (int t = 0; t < 6; ++t) {
        const int colE = t*16 + arow;
        f32x4 acc = {0.f,0.f,0.f,0.f};
        acc = __builtin_amdgcn_mfma_f32_16x16x32_bf16(ae0, Ba1[t][0], acc, 0, 0, 0);
        acc = __builtin_amdgcn_mfma_f32_16x16x32_bf16(ae1, Ba1[t][1], acc, 0, 0, 0);
        const float bav = ba[colE];
        if (q4 == 0) {
          #pragma unroll
          for (int j = 0; j < 4; ++j) att[j*ATS + colE] = f2bf(fsigm(acc[j] + bav));
        } else if (q4 == 1) {
          att[4*ATS + colE] = f2bf(fsigm(acc[0] + bav));
        }
      }
      bf16x8 Ba2[8][2];
      #pragma unroll
      for (int t = 0; t < 8; ++t)
        #pragma unroll
        for (int ks = 0; ks < 2; ++ks)
          Ba2[t][ks] = get_ba<USE_WS>(wsf, Wa, 8 + t, ks, l);
      #pragma unroll
      for (int t = 6; t < 8; ++t) {
        const int colE = t*16 + arow;
        f32x4 acc = {0.f,0.f,0.f,0.f};
        acc = __builtin_amdgcn_mfma_f32_16x16x32_bf16(ae0, Ba1[t][0], acc, 0, 0, 0);
        acc = __builtin_amdgcn_mfma_f32_16x16x32_bf16(ae1, Ba1[t][1], acc, 0, 0, 0);
        const float bav = ba[colE];
        if (q4 == 0) {
          #pragma unroll
          for (int j = 0; j < 4; ++j) att[j*ATS + colE] = f2bf(fsigm(acc[j] + bav));
        } else if (q4 == 1) {
          att[4*ATS + colE] = f2bf(fsigm(acc[0] + bav));
        }
      }
      #pragma unroll
      for (int t = 0; t < 8; ++t) {
        const int colE = (8 + t)*16 + arow;
        f32x4 acc = {0.f,0.f,0.f,0.f};
        acc = __builtin_amdgcn_mfma_f32_16x16x32_bf16(ae0, Ba2[t][0], acc, 0, 0, 0);
        acc = __builtin_amdgcn_mfma_f32_16x16x32_bf16(ae1, Ba2[t][1], acc, 0, 0, 0);
        const float bav = ba[colE];
        if (q4 == 0) {
          #pragma unroll
          for (int j = 0; j < 4; ++j) att[j*ATS + colE] = f2bf(fsigm(acc[j] + bav));
        } else if (q4 == 1) {
          att[4*ATS + colE] = f2bf(fsigm(acc[0] + bav));
        }
      }
    }
  }
  __syncthreads();                                   // bar3: mid -> F (att cross-wave)

  // ---- Phase F (all waves): out = bf16(x) * att, b64 LDS reads + dwordx4 stores ----
  {
    float* og = out + (size_t)b*4352;
    constexpr int GOF[17] = {0,0,0,0,0,1,2,1,2,1,2,3,4,3,4,3,4};
    auto emit = [&](int k){
      const bf16x4 xv4 = *(const bf16x4*)&xbf[k*XBSTR + c4];
      const bf16x4 a4  = *(const bf16x4*)&att[GOF[k]*ATS + c4];
      v4f o;
      o.x = bf2f(xv4[0]) * bf2f(a4[0]);
      o.y = bf2f(xv4[1]) * bf2f(a4[1]);
      o.z = bf2f(xv4[2]) * bf2f(a4[2]);
      o.w = bf2f(xv4[3]) * bf2f(a4[3]);
      *(v4f*)&og[k*256 + c4] = o;
    };
    emit(r0);      emit(r0 + 4);
    emit(r0 + 8);  emit(r0 + 12);
    if (tid < 64) emit(16);
  }
}

extern "C" void kernel_launch(void* const* d_in, const int* in_sizes, int n_in,
                              void* d_out, int out_size, void* d_ws, size_t ws_size,
                              hipStream_t stream) {
    (void)n_in; (void)out_size;
    const float* x   = (const float*)d_in[0];
    const float* Wd  = (const float*)d_in[1];
    const float* bd  = (const float*)d_in[2];
    const float* s1  = (const float*)d_in[3];
    const float* b1  = (const float*)d_in[4];
    const float* m1  = (const float*)d_in[5];
    const float* v1  = (const float*)d_in[6];
    const float* Wc  = (const float*)d_in[7];
    const float* s2  = (const float*)d_in[8];
    const float* b2  = (const float*)d_in[9];
    const float* m2  = (const float*)d_in[10];
    const float* v2  = (const float*)d_in[11];
    const float* Wa  = (const float*)d_in[12];
    const float* ba  = (const float*)d_in[13];

    const int Btot = in_sizes[0] / (17 * 256);   // 4096 -> one block per batch
    bf16x8* wsf = (bf16x8*)d_ws;

    if (ws_size >= (size_t)FRAG_SLOTS * 16) {
        pack_frags<<<FRAG_SLOTS/256, 256, 0, stream>>>(Wd, Wc, Wa, wsf);
        fused_gnn_v16<true><<<Btot, 256, 0, stream>>>(
            x, Wd, bd, s1, b1, m1, v1, Wc, s2, b2, m2, v2, Wa, ba,
            wsf, (float*)d_out);
    } else {
        fused_gnn_v16<false><<<Btot, 256, 0, stream>>>(
            x, Wd, bd, s1, b1, m1, v1, Wc, s2, b2, m2, v2, Wa, ba,
            wsf, (float*)d_out);
    }
}

// Round 19
// 45.915 us; speedup vs baseline: 3.0432x; 1.4757x over previous
//
#include <hip/hip_runtime.h>

typedef float  v4f    __attribute__((ext_vector_type(4)));
typedef float  f32x4  __attribute__((ext_vector_type(4)));
typedef short  bf16x8 __attribute__((ext_vector_type(8)));
typedef short  bf16x4 __attribute__((ext_vector_type(4)));

namespace {
constexpr int XBSTR = 264;   // xbf row stride (shorts); rows 0-16 batch0, 17-33 batch1, 34 garbage
constexpr int XDT   = 48;    // xdT col stride (shorts); 96 B, vec reads at idx 0/8/24/32 are 16B-aligned
constexpr int MWC   = 129;   // mw row stride (f32)
constexpr int ATS   = 260;   // att row stride (shorts)
constexpr int MSTR  = 72;    // mbf/abf row stride (shorts)
constexpr int FRAG_SLOTS = 5120;

__device__ __forceinline__ float fsilu(float v){ return v/(1.f+__expf(-v)); }
__device__ __forceinline__ float fsigm(float v){ return 1.f/(1.f+__expf(-v)); }

__device__ __forceinline__ unsigned f2bf2(float a, float b){
  unsigned r;
  asm("v_cvt_pk_bf16_f32 %0, %1, %2" : "=v"(r) : "v"(a), "v"(b));
  return r;
}
__device__ __forceinline__ short f2bf(float f){   // scalar RNE, matches cvt_pk
  unsigned u = __builtin_bit_cast(unsigned, f);
  return (short)((u + 0x7FFFu + ((u>>16)&1u)) >> 16);
}
__device__ __forceinline__ float bf2f(short s){
  unsigned u = ((unsigned)(unsigned short)s) << 16;
  return __builtin_bit_cast(float, u);
}

template<bool USE_WS>
__device__ __forceinline__ bf16x8 get_bd(const bf16x8* wsf, const float* Wd,
                                         int nt, int ks, int l){
  if constexpr (USE_WS) return wsf[(nt*8 + ks)*64 + l];
  bf16x8 f;
  #pragma unroll
  for (int j = 0; j < 8; ++j) f[j] = f2bf(Wd[(ks*32 + (l>>4)*8 + j)*64 + nt*16 + (l&15)]);
  return f;
}
template<bool USE_WS>
__device__ __forceinline__ bf16x8 get_bc(const bf16x8* wsf, const float* Wc,
                                         int nt, int ks, int l){
  if constexpr (USE_WS) return wsf[2048 + (nt*2 + ks)*64 + l];
  const int col = nt*16 + (l&15), cw = col>>6, co = col&63;
  bf16x8 f;
  #pragma unroll
  for (int j = 0; j < 8; ++j) f[j] = f2bf(Wc[co*128 + cw*64 + ks*32 + (l>>4)*8 + j]);
  return f;
}
template<bool USE_WS>
__device__ __forceinline__ bf16x8 get_ba(const bf16x8* wsf, const float* Wa,
                                         int nt, int ks, int l){
  if constexpr (USE_WS) return wsf[3072 + (nt*2 + ks)*64 + l];
  const int col = nt*16 + (l&15);
  bf16x8 f;
  #pragma unroll
  for (int j = 0; j < 8; ++j) f[j] = f2bf(Wa[(ks*32 + (l>>4)*8 + j)*256 + col]);
  return f;
}
}

__global__ __launch_bounds__(256)
void pack_frags(const float* __restrict__ Wd, const float* __restrict__ Wc,
                const float* __restrict__ Wa, bf16x8* __restrict__ wsf)
{
  const int e  = blockIdx.x*256 + threadIdx.x;      // 0..5119
  const int l  = e & 63;
  const int fi = e >> 6;                            // 0..79
  bf16x8 f;
  if (fi < 32) {                                    // Bd: nt(4) x ks(8)
    const int nt = fi >> 3, ks = fi & 7;
    #pragma unroll
    for (int j = 0; j < 8; ++j) f[j] = f2bf(Wd[(ks*32 + (l>>4)*8 + j)*64 + nt*16 + (l&15)]);
  } else if (fi < 48) {                             // Bc: nt(8) x ks(2)
    const int idx = fi - 32, nt = idx >> 1, ks = idx & 1;
    const int col = nt*16 + (l&15), cw = col>>6, co = col&63;
    #pragma unroll
    for (int j = 0; j < 8; ++j) f[j] = f2bf(Wc[co*128 + cw*64 + ks*32 + (l>>4)*8 + j]);
  } else {                                          // Ba: nt(16) x ks(2)
    const int idx = fi - 48, nt = idx >> 1, ks = idx & 1;
    const int col = nt*16 + (l&15);
    #pragma unroll
    for (int j = 0; j < 8; ++j) f[j] = f2bf(Wa[(ks*32 + (l>>4)*8 + j)*256 + col]);
  }
  wsf[e] = f;
}

// v17: TWO batches stacked in the M dimension; 6 barriers per 2 batches.
template<bool USE_WS>
__global__ __launch_bounds__(256, 6)
void fused_gnn_v17(const float* __restrict__ x,
                   const float* __restrict__ Wd, const float* __restrict__ bd,
                   const float* __restrict__ bn1s, const float* __restrict__ bn1b,
                   const float* __restrict__ bn1m, const float* __restrict__ bn1v,
                   const float* __restrict__ Wc,
                   const float* __restrict__ bn2s, const float* __restrict__ bn2b,
                   const float* __restrict__ bn2m, const float* __restrict__ bn2v,
                   const float* __restrict__ Wa, const float* __restrict__ ba,
                   const bf16x8* __restrict__ wsf,
                   float* __restrict__ out)
{
  // 33.6 KB static LDS -> 4 blocks/CU
  __shared__ short xbf[35*XBSTR];                   // 18480 B
  __shared__ __align__(16) char uni_raw[6144];      // union: xdT bf16[64][48] | att bf16[10][260]
  __shared__ float mw[10*MWC];                      // 5160 B
  __shared__ short mbf[16*MSTR];                    // rows 10-15 garbage
  __shared__ short abf[16*MSTR];

  short* xdT = (short*)uni_raw;
  short* att = (short*)uni_raw;

  const int tid  = threadIdx.x;
  const int l    = tid & 63;
  const int wv   = tid >> 6;            // wave 0..3
  const int arow = l & 15;
  const int ak8  = (l >> 4) * 8;
  const int b0   = blockIdx.x * 2;      // two batches stacked in M
  const int colA = wv*16 + arow;

  // ---- per-lane BN affines in registers (b_down folded into bn1 bias) ----
  const float a1r = bn1s[colA] * rsqrtf(bn1v[colA] + 1e-5f);
  const float b1r = (bd[colA] - bn1m[colA])*a1r + bn1b[colA];
  const float a2r = bn2s[l] * rsqrtf(bn2v[l] + 1e-5f);
  const float b2r = bn2b[l] - bn2m[l]*a2r;

  // ---- stage both batches -> bf16 LDS rows 0..33 (coalesced float4) ----
  {
    const v4f* x4 = (const v4f*)(x + (size_t)b0 * 4352);
    #pragma unroll
    for (int s = 0; s < 9; ++s) {
      const int idx = s*256 + tid;                  // float4 index over 2x1088
      if (idx < 2176) {
        const v4f v = x4[idx];
        const int q   = idx >= 1088;
        const int e   = idx - q*1088;
        const int row = q*17 + (e >> 6);
        const int cc  = (e & 63) * 4;
        uint2 u; u.x = f2bf2(v.x, v.y); u.y = f2bf2(v.z, v.w);
        *(uint2*)&xbf[row*XBSTR + cc] = u;
      }
    }
  }
  __syncthreads();                                   // bar1: stage -> A

  // ---- Phase A (MFMA): M=34 (3 m-tiles), N=64, K=256; epilogue -> xdT ----
  // xdT col index map: idx(r) = r<17 ? r : r+7  (batch1 at 24..40, vec-aligned)
  {
    f32x4 acc0 = {0.f,0.f,0.f,0.f};                  // rows 0..15
    f32x4 acc1 = {0.f,0.f,0.f,0.f};                  // rows 16..31
    f32x4 acc2 = {0.f,0.f,0.f,0.f};                  // rows 32..33 (+garbage)
    const int rowT2 = (arow < 2) ? (32 + arow) : 34;
    #pragma unroll
    for (int h = 0; h < 2; ++h) {
      bf16x8 Bd[4];
      #pragma unroll
      for (int k4 = 0; k4 < 4; ++k4) Bd[k4] = get_bd<USE_WS>(wsf, Wd, wv, h*4 + k4, l);
      #pragma unroll
      for (int k4 = 0; k4 < 4; ++k4) {
        const int ks = h*4 + k4;
        bf16x8 a0 = *(const bf16x8*)&xbf[arow*XBSTR + ks*32 + ak8];
        acc0 = __builtin_amdgcn_mfma_f32_16x16x32_bf16(a0, Bd[k4], acc0, 0, 0, 0);
        bf16x8 a1 = *(const bf16x8*)&xbf[(16 + arow)*XBSTR + ks*32 + ak8];
        acc1 = __builtin_amdgcn_mfma_f32_16x16x32_bf16(a1, Bd[k4], acc1, 0, 0, 0);
        bf16x8 a2 = *(const bf16x8*)&xbf[rowT2*XBSTR + ks*32 + ak8];
        acc2 = __builtin_amdgcn_mfma_f32_16x16x32_bf16(a2, Bd[k4], acc2, 0, 0, 0);
      }
    }
    // epilogue: silu(bn1(.)) -> xdT column colA
    {
      const float s0 = fsilu(acc0[0]*a1r + b1r);
      const float s1 = fsilu(acc0[1]*a1r + b1r);
      const float s2 = fsilu(acc0[2]*a1r + b1r);
      const float s3 = fsilu(acc0[3]*a1r + b1r);
      uint2 u; u.x = f2bf2(s0, s1); u.y = f2bf2(s2, s3);
      *(uint2*)&xdT[colA*XDT + (l>>4)*4] = u;        // idx 0..15, consecutive
    }
    {
      #pragma unroll
      for (int j = 0; j < 4; ++j) {
        const int r = 16 + (l>>4)*4 + j;             // 16..31
        const int idx = (r < 17) ? r : r + 7;        // 16, 24..38
        xdT[colA*XDT + idx] = f2bf(fsilu(acc1[j]*a1r + b1r));
      }
      if ((l >> 4) == 0) {
        #pragma unroll
        for (int j = 0; j < 2; ++j) {
          const int r = 32 + j;                      // 32,33 -> idx 39,40
          xdT[colA*XDT + r + 7] = f2bf(fsilu(acc2[j]*a1r + b1r));
        }
      }
    }
  }
  __syncthreads();                                   // bar2: A -> B1 (xdT cross-wave)

  // ---- prefetch B2 weight frags (latency covered by B1 + bar3) ----
  bf16x8 BcT[2][2];
  #pragma unroll
  for (int t = 0; t < 2; ++t)
    #pragma unroll
    for (int ks = 0; ks < 2; ++ks)
      BcT[t][ks] = get_bc<USE_WS>(wsf, Wc, wv*2 + t, ks, l);

  // ---- Phase B1: wave 0 -> batch 0 means, wave 1 -> batch 1 means ----
  if (wv < 2) {
    const int base = wv * 24;                        // 0 or 24
    const bf16x8 rA = *(const bf16x8*)&xdT[l*XDT + base];
    const bf16x8 rB = *(const bf16x8*)&xdT[l*XDT + base + 8];
    const float xlast = bf2f(xdT[l*XDT + base + 16]);
    float xv[16];
    #pragma unroll
    for (int k = 0; k < 8; ++k) { xv[k] = bf2f(rA[k]); xv[k+8] = bf2f(rB[k]); }
    const float m0 = (xv[0]+xv[1]+xv[2]+xv[3]+xv[4])*0.2f;
    const float m1 = (xv[5]+xv[7]+xv[9])*(1.f/3.f);
    const float m2 = (xv[6]+xv[8]+xv[10])*(1.f/3.f);
    const float m3 = (xv[11]+xv[13]+xv[15])*(1.f/3.f);
    const float m4 = (xv[12]+xv[14]+xlast)*(1.f/3.f);
    const int qb = wv*5;
    const unsigned p01 = f2bf2(m0, m1);
    const unsigned p23 = f2bf2(m2, m3);
    mbf[(qb+0)*MSTR + l] = (short)(p01 & 0xFFFFu);
    mbf[(qb+1)*MSTR + l] = (short)(p01 >> 16);
    mbf[(qb+2)*MSTR + l] = (short)(p23 & 0xFFFFu);
    mbf[(qb+3)*MSTR + l] = (short)(p23 >> 16);
    mbf[(qb+4)*MSTR + l] = f2bf(m4);
  }
  __syncthreads();                                   // bar3: B1 -> B2 (mbf cross-wave)

  // ---- Phase B2 (MFMA): mw = means @ [Wc1|Wc2], M=10, N=128, wave owns 2 n-tiles ----
  {
    bf16x8 am[2];
    #pragma unroll
    for (int ks = 0; ks < 2; ++ks)
      am[ks] = *(const bf16x8*)&mbf[arow*MSTR + ks*32 + ak8];
    #pragma unroll
    for (int t = 0; t < 2; ++t) {
      const int nt = wv*2 + t;
      f32x4 acc = {0.f,0.f,0.f,0.f};
      #pragma unroll
      for (int ks = 0; ks < 2; ++ks)
        acc = __builtin_amdgcn_mfma_f32_16x16x32_bf16(am[ks], BcT[t][ks], acc, 0, 0, 0);
      const int q4 = l >> 4;
      if (q4 == 0) {
        #pragma unroll
        for (int j = 0; j < 4; ++j) mw[j*MWC + nt*16 + arow] = acc[j];
      } else if (q4 == 1) {
        #pragma unroll
        for (int j = 0; j < 4; ++j) mw[(4+j)*MWC + nt*16 + arow] = acc[j];
      } else if (q4 == 2) {
        mw[8*MWC + nt*16 + arow] = acc[0];
        mw[9*MWC + nt*16 + arow] = acc[1];
      }
    }
  }
  __syncthreads();                                   // bar4: B2 -> B3 (mw cross-wave)

  // ---- prefetch phase-E weight frags (latency covered by B3 + bar5) ----
  bf16x8 BaT[4][2];
  #pragma unroll
  for (int t = 0; t < 4; ++t)
    #pragma unroll
    for (int ks = 0; ks < 2; ++ks)
      BaT[t][ks] = get_ba<USE_WS>(wsf, Wa, wv*4 + t, ks, l);

  // ---- Phase B3: agg; wave wv -> g=wv (both batches); wave 0 also g=4 ----
  {
    const int o = l;
    auto doQ = [&](int q, int g, bool also4){
      float m2c[5];
      #pragma unroll
      for (int cc = 0; cc < 5; ++cc) m2c[cc] = mw[(q*5+cc)*MWC + 64 + o];
      {
        const float bse = mw[(q*5+g)*MWC + o] - m2c[g];
        float s = 0.f;
        #pragma unroll
        for (int cc = 0; cc < 5; ++cc)
          if (cc != g) s += fsilu((bse + m2c[cc])*a2r + b2r);
        abf[(q*5+g)*MSTR + o] = f2bf(s);
      }
      if (also4) {
        const float bse = mw[(q*5+4)*MWC + o] - m2c[4];
        float s = 0.f;
        #pragma unroll
        for (int cc = 0; cc < 4; ++cc)
          s += fsilu((bse + m2c[cc])*a2r + b2r);
        abf[(q*5+4)*MSTR + o] = f2bf(s);
      }
    };
    if (wv == 0) { doQ(0, 0, true); doQ(1, 0, true); }
    else         { doQ(0, wv, false); doQ(1, wv, false); }
  }
  __syncthreads();                                   // bar5: B3 -> E (abf cross-wave)

  // ---- Phase E (MFMA): att = sigmoid(agg @ Wa + ba), M=10, N=256 ----
  {
    bf16x8 ae[2];
    #pragma unroll
    for (int ks = 0; ks < 2; ++ks)
      ae[ks] = *(const bf16x8*)&abf[arow*MSTR + ks*32 + ak8];
    #pragma unroll
    for (int t = 0; t < 4; ++t) {
      const int nt = wv*4 + t;
      const int colE = nt*16 + arow;
      f32x4 acc = {0.f,0.f,0.f,0.f};
      #pragma unroll
      for (int ks = 0; ks < 2; ++ks)
        acc = __builtin_amdgcn_mfma_f32_16x16x32_bf16(ae[ks], BaT[t][ks], acc, 0, 0, 0);
      const float bav = ba[colE];
      const int q4 = l >> 4;
      if (q4 == 0) {
        #pragma unroll
        for (int j = 0; j < 4; ++j)
          att[j*ATS + colE] = f2bf(fsigm(acc[j] + bav));
      } else if (q4 == 1) {
        #pragma unroll
        for (int j = 0; j < 4; ++j)
          att[(4+j)*ATS + colE] = f2bf(fsigm(acc[j] + bav));
      } else if (q4 == 2) {
        att[8*ATS + colE] = f2bf(fsigm(acc[0] + bav));
        att[9*ATS + colE] = f2bf(fsigm(acc[1] + bav));
      }
    }
  }
  __syncthreads();                                   // bar6: E -> F (att cross-wave)

  // ---- Phase F: out = bf16(x)[xbf] * att, dwordx4 stores, both batches ----
  {
    constexpr int GOF[17] = {0,0,0,0,0,1,2,1,2,1,2,3,4,3,4,3,4};
    #pragma unroll
    for (int s = 0; s < 9; ++s) {
      const int idx = s*256 + tid;
      if (idx < 2176) {
        const int q   = idx >= 1088;
        const int e   = idx - q*1088;
        const int k   = e >> 6;
        const int cc  = (e & 63) * 4;
        const bf16x4 xv4 = *(const bf16x4*)&xbf[(q*17 + k)*XBSTR + cc];
        const bf16x4 a4  = *(const bf16x4*)&att[(q*5 + GOF[k])*ATS + cc];
        v4f o;
        o.x = bf2f(xv4[0]) * bf2f(a4[0]);
        o.y = bf2f(xv4[1]) * bf2f(a4[1]);
        o.z = bf2f(xv4[2]) * bf2f(a4[2]);
        o.w = bf2f(xv4[3]) * bf2f(a4[3]);
        *(v4f*)&out[(size_t)(b0+q)*4352 + (size_t)e*4] = o;
      }
    }
  }
}

extern "C" void kernel_launch(void* const* d_in, const int* in_sizes, int n_in,
                              void* d_out, int out_size, void* d_ws, size_t ws_size,
                              hipStream_t stream) {
    (void)n_in; (void)out_size;
    const float* x   = (const float*)d_in[0];
    const float* Wd  = (const float*)d_in[1];
    const float* bd  = (const float*)d_in[2];
    const float* s1  = (const float*)d_in[3];
    const float* b1  = (const float*)d_in[4];
    const float* m1  = (const float*)d_in[5];
    const float* v1  = (const float*)d_in[6];
    const float* Wc  = (const float*)d_in[7];
    const float* s2  = (const float*)d_in[8];
    const float* b2  = (const float*)d_in[9];
    const float* m2  = (const float*)d_in[10];
    const float* v2  = (const float*)d_in[11];
    const float* Wa  = (const float*)d_in[12];
    const float* ba  = (const float*)d_in[13];

    const int Btot = in_sizes[0] / (17 * 256);   // 4096
    const int GRID = Btot / 2;                   // 2048 blocks, 2 batches stacked
    bf16x8* wsf = (bf16x8*)d_ws;

    if (ws_size >= (size_t)FRAG_SLOTS * 16) {
        pack_frags<<<FRAG_SLOTS/256, 256, 0, stream>>>(Wd, Wc, Wa, wsf);
        fused_gnn_v17<true><<<GRID, 256, 0, stream>>>(
            x, Wd, bd, s1, b1, m1, v1, Wc, s2, b2, m2, v2, Wa, ba,
            wsf, (float*)d_out);
    } else {
        fused_gnn_v17<false><<<GRID, 256, 0, stream>>>(
            x, Wd, bd, s1, b1, m1, v1, Wc, s2, b2, m2, v2, Wa, ba,
            wsf, (float*)d_out);
    }
}